// Round 6
// baseline (242.109 us; speedup 1.0000x reference)
//
#include <hip/hip_runtime.h>
#include <stdint.h>

// RNN: h_t = tanh(x_t W_ih^T + b_ih + b_hh + h_{t-1} W_hh^T)
// out[b,t] = W_fc . h_t + b_fc ;  hidden = h_T.  B=8192, T=512, I=H=7. fp32.
//
// R12: 16 lanes/chain -> 4 chains/wave -> 2048 waves = 2 waves/SIMD, all
// self-sufficient (no barriers, no LDS). R6-R11 showed: busy-time ~32us is
// conserved; 1 wave/SIMD leaves ~50-65% stall that chain-shortening does NOT
// fix; barrier-coupled wave pairs made it worse. This gets a second
// INDEPENDENT instruction stream on every SIMD to hide trans/DPP/VMEM
// latency, while splitting each row's dot across 2 lanes to keep per-wave
// issue ~flat.
// Quad layout per 16-lane group (q = quad, j = lane&3):
//   Q0: rows0-3 terms0-3 | Q1: rows4-7 terms0-3
//   Q2: rows0-3 terms4-7 | Q3: rows4-7 terms4-7   (row = ((q&1)<<2)|j)
// Step: 4-term partial tree -> acc += row_ror:8(acc) (self-inverse combine;
// both half-quads hold the full pre-activation) -> exp2/rcp (r-carry algebra
// from R11: h = 1-2r, weights pre-scaled by -2c, c=2/ln2) -> broadcast
// d_j = quad_perm_j(r), e_j = row_ror:4(d_j) (direction-proof because r is
// duplicated across quad pairs) -> next tree with per-lane zero-padded
// weights selecting d vs e. Out: rotation reduce xor1,xor2,ror4,ror8 (sums
// all 16 lanes for any rotation direction), x0.5 dup factor folded into wfc.
// x prefetch: R6's proven asm XChunk machinery, verbatim.

#define B_TOTAL 8192
#define T_STEPS 512

#define DPP_Q0   0x00        // quad_perm [0,0,0,0]
#define DPP_Q1   0x55
#define DPP_Q2   0xAA
#define DPP_Q3   0xFF
#define DPP_XOR1 0xB1        // quad_perm [1,0,3,2]
#define DPP_XOR2 0x4E        // quad_perm [2,3,0,1]
#define DPP_ROR4 0x124       // row_ror:4  (within 16-lane row)
#define DPP_ROR8 0x128       // row_ror:8  (within 16-lane row, self-inverse)

template <int CTRL>
__device__ __forceinline__ float dpp_mov(float v) {
    int s = __float_as_int(v);
    return __int_as_float(__builtin_amdgcn_update_dpp(s, s, CTRL, 0xF, 0xF, true));
}

typedef float v4f __attribute__((ext_vector_type(4)));

struct XChunk { v4f v[14]; };   // 8 steps * 7 floats = 56 floats = 224 B

__device__ __forceinline__ void chunk_issue(XChunk& ch, const float* base) {
    #pragma unroll
    for (int i = 0; i < 14; ++i)
        asm volatile("global_load_dwordx4 %0, %1, off offset:%2"
                     : "=v"(ch.v[i]) : "v"(base), "i"(16 * i));
}

#define CHUNK_WAIT(ch, N)                                                     \
    asm volatile("s_waitcnt vmcnt(" #N ")"                                    \
        : "+v"((ch).v[0]), "+v"((ch).v[1]), "+v"((ch).v[2]), "+v"((ch).v[3]), \
          "+v"((ch).v[4]), "+v"((ch).v[5]), "+v"((ch).v[6]), "+v"((ch).v[7]), \
          "+v"((ch).v[8]), "+v"((ch).v[9]), "+v"((ch).v[10]),                 \
          "+v"((ch).v[11]), "+v"((ch).v[12]), "+v"((ch).v[13]))

__global__ __launch_bounds__(256, 2) void rnn_kernel(
    const float* __restrict__ x,    // [B, T, I]
    const float* __restrict__ Wih,  // [H, I]
    const float* __restrict__ Whh,  // [H, H]
    const float* __restrict__ bih,  // [H]
    const float* __restrict__ bhh,  // [H]
    const float* __restrict__ Wfc,  // [1, H]
    const float* __restrict__ bfc,  // [1]
    float* __restrict__ out)        // [B*T] out, then [B*H] hidden
{
    const int tid  = threadIdx.x;
    const int lane = tid & 63;
    const int p    = lane & 15;           // position in 16-lane chain group
    const int q    = p >> 2;              // quad 0..3
    const int j    = p & 3;
    const int row  = ((q & 1) << 2) | j;  // 0..7 (7 = dummy)
    const bool lowq = (q < 2);            // handles terms 0-3 (+bias)
    const int b    = blockIdx.x * 16 + (tid >> 4);

    const float C2L = 2.8853900817779268f;   // 2/ln2

    // ---- per-lane weights (all VMEM loads BEFORE any asm prefetch) ----
    float wu[7];
    #pragma unroll
    for (int i = 0; i < 7; ++i) wu[i] = 0.0f;
    float useed = 0.0f, wfch = 0.0f;
    float wd[4] = {0.f, 0.f, 0.f, 0.f}, we[4] = {0.f, 0.f, 0.f, 0.f};
    float obase;
    {
        float Wp[8];                      // W'[row][c] = -2c*Whh, col7 = 0
        #pragma unroll
        for (int i = 0; i < 8; ++i) Wp[i] = 0.0f;
        if (row < 7) {
            float srow = 0.0f;
            #pragma unroll
            for (int c = 0; c < 7; ++c) {
                float wr = Whh[row * 7 + c];
                Wp[c] = -2.0f * C2L * wr;
                srow += wr;
            }
            if (lowq) {
                #pragma unroll
                for (int c = 0; c < 4; ++c) wu[c] = C2L * Wih[row * 7 + c];
                // z' = c*z with h=1-2r folded: bias' = c*(bih+bhh+sum_c Whh)
                useed = C2L * (bih[row] + bhh[row] + srow);
            } else {
                #pragma unroll
                for (int c = 4; c < 7; ++c) wu[c] = C2L * Wih[row * 7 + c];
            }
            wfch = -Wfc[row];             // -2*wfc * 0.5 (each row on 2 lanes)
        }
        // d_j holds r_{j} on Q0/Q2, r_{4+j} on Q1/Q3; e_j the complement.
        #pragma unroll
        for (int jj = 0; jj < 4; ++jj) {
            float lo = Wp[jj], hi = Wp[4 + jj];
            wd[jj] = (q == 0) ? lo : (q == 3) ? hi : 0.0f;
            we[jj] = (q == 1) ? lo : (q == 2) ? hi : 0.0f;
        }
        float sw = 0.0f;
        #pragma unroll
        for (int r7 = 0; r7 < 7; ++r7) sw += Wfc[r7];
        obase = bfc[0] + sw;              // bfc + sum wfc (h = 1-2r fold)
    }

    const float* xrow = x + (size_t)b * (T_STEPS * 7);   // 3584 floats
    float* outp = out + (size_t)b * T_STEPS;

    float rk = 0.5f;                      // r state (h0 = 0 <=> r0 = 0.5)

    XChunk A, B;
    chunk_issue(A, xrow);                 // chunk 0
    chunk_issue(B, xrow + 56);            // chunk 1

    auto do_chunk = [&](XChunk& buf, int c, const float* reload) {
        // ---- parallel phase: u-partials for 8 steps ----
        float u[8];
        {
            float xv[56];
            #pragma unroll
            for (int i = 0; i < 14; ++i) {
                xv[4 * i + 0] = buf.v[i].x; xv[4 * i + 1] = buf.v[i].y;
                xv[4 * i + 2] = buf.v[i].z; xv[4 * i + 3] = buf.v[i].w;
            }
            #pragma unroll
            for (int s = 0; s < 8; ++s) {
                const float* xs = &xv[s * 7];
                float acc = useed;
                #pragma unroll
                for (int c7 = 0; c7 < 7; ++c7)
                    acc = __builtin_fmaf(wu[c7], xs[c7], acc);
                u[s] = acc;
            }
        }
        if (reload) chunk_issue(buf, reload);   // in flight across the 8 steps

        // ---- serial phase: 8 recurrence steps ----
        float o[8];
        #pragma unroll
        for (int s = 0; s < 8; ++s) {
            // broadcast previous r: d_j intra-quad, e_j cross-quad (ror4)
            float d0 = dpp_mov<DPP_Q0>(rk), d1 = dpp_mov<DPP_Q1>(rk);
            float d2 = dpp_mov<DPP_Q2>(rk), d3 = dpp_mov<DPP_Q3>(rk);
            float e0 = dpp_mov<DPP_ROR4>(d0), e1 = dpp_mov<DPP_ROR4>(d1);
            float e2 = dpp_mov<DPP_ROR4>(d2), e3 = dpp_mov<DPP_ROR4>(d3);
            float aa = __builtin_fmaf(wd[0], d0, u[s]);
            aa = __builtin_fmaf(wd[1], d1, aa);
            float bb = wd[2] * d2; bb = __builtin_fmaf(wd[3], d3, bb);
            float cc = we[0] * e0; cc = __builtin_fmaf(we[1], e1, cc);
            float gg = we[2] * e2; gg = __builtin_fmaf(we[3], e3, gg);
            float acc = (aa + bb) + (cc + gg);
            acc += dpp_mov<DPP_ROR8>(acc);        // combine the two half-dots
            float ee = __builtin_amdgcn_exp2f(acc);
            rk = __builtin_amdgcn_rcpf(ee + 1.0f);
            // out-projection: rotation reduce over 16 lanes (off the chain)
            float v = wfch * rk;
            v += dpp_mov<DPP_XOR1>(v);
            v += dpp_mov<DPP_XOR2>(v);
            v += dpp_mov<DPP_ROR4>(v);
            v += dpp_mov<DPP_ROR8>(v);
            o[s] = v + obase;
        }
        if (p == 15) {
            *(float4*)(outp + c * 8 + 0) = make_float4(o[0], o[1], o[2], o[3]);
            *(float4*)(outp + c * 8 + 4) = make_float4(o[4], o[5], o[6], o[7]);
        }
    };

    // Steady loop: chunks 0..61; reloads c+2 (<=62) and c+3 (<=63) valid.
    #pragma unroll 1
    for (int c = 0; c < 62; c += 2) {
        CHUNK_WAIT(A, 14);                         // A(c) oldest -> drained
        do_chunk(A, c, xrow + (c + 2) * 56);
        CHUNK_WAIT(B, 14);                         // B(c+1) oldest -> drained
        do_chunk(B, c + 1, xrow + (c + 3) * 56);
    }
    CHUNK_WAIT(A, 14);
    do_chunk(A, 62, nullptr);
    CHUNK_WAIT(B, 0);
    do_chunk(B, 63, nullptr);

    // hidden h_T: rows0-3 live on Q0 (p=j), rows4-6 on Q1 (p=4+j); h = 1-2r
    if (p < 8 && row < 7) {
        out[(size_t)B_TOTAL * T_STEPS + (size_t)b * 7 + row] =
            __builtin_fmaf(-2.0f, rk, 1.0f);
    }
}

extern "C" void kernel_launch(void* const* d_in, const int* in_sizes, int n_in,
                              void* d_out, int out_size, void* d_ws, size_t ws_size,
                              hipStream_t stream) {
    const float* x   = (const float*)d_in[0];
    const float* Wih = (const float*)d_in[1];
    const float* Whh = (const float*)d_in[2];
    const float* bih = (const float*)d_in[3];
    const float* bhh = (const float*)d_in[4];
    const float* Wfc = (const float*)d_in[5];
    const float* bfc = (const float*)d_in[6];
    float* out = (float*)d_out;

    // 16 chains/block (4 waves x 4 chains); 512 blocks -> 2 blocks/CU
    // -> 8 waves/CU -> 2 independent waves/SIMD (no barriers anywhere).
    rnn_kernel<<<dim3(B_TOTAL / 16), dim3(256), 0, stream>>>(
        x, Wih, Whh, bih, bhh, Wfc, bfc, out);
}